// Round 12
// baseline (207.342 us; speedup 1.0000x reference)
//
#include <hip/hip_runtime.h>
#include <math.h>

#define B_ 32
#define Q_ 1024
#define G_ 64
#define T_ 256    // build threads (4 waves); matcher runs on wave 0 only
#define K16 16    // columns per lane in matcher (Q_ / 64)
#define LROWS 32  // cost rows resident in LDS

// ---- cross-lane helpers -------------------------------------------------
template<int CTRL>
__device__ __forceinline__ double dpp_f64(double x) {
    union { double d; int i[2]; } a; a.d = x;
    union { int i[2]; double d; } r;
    r.i[0] = __builtin_amdgcn_update_dpp(a.i[0], a.i[0], CTRL, 0xF, 0xF, false);
    r.i[1] = __builtin_amdgcn_update_dpp(a.i[1], a.i[1], CTRL, 0xF, 0xF, false);
    return r.d;
}
template<int CTRL>
__device__ __forceinline__ float dpp_f32(float x) {
    union { float f; int i; } a; a.f = x;
    union { int i; float f; } r;
    r.i = __builtin_amdgcn_update_dpp(a.i, a.i, CTRL, 0xF, 0xF, false);
    return r.f;
}
#define ROR1 0x121
#define ROR2 0x122
#define ROR4 0x124
#define ROR8 0x128
#define BC15 0x142   // row_bcast15: row r's lane15 -> row r+1
#define BC31 0x143   // row_bcast31: lane31 -> rows 2,3

__device__ __forceinline__ double readlane_f64(double x, int sl) {
    const int s = __builtin_amdgcn_readfirstlane(sl);
    union { double d; int i2[2]; } a; a.d = x;
    union { int i2[2]; double d; } r;
    r.i2[0] = __builtin_amdgcn_readlane(a.i2[0], s);
    r.i2[1] = __builtin_amdgcn_readlane(a.i2[1], s);
    return r.d;
}
__device__ __forceinline__ float readlane_f32(float x, int sl) {
    union { float f; int i; } a; a.f = x;
    union { int i; float f; } r;
    r.i = __builtin_amdgcn_readlane(a.i, sl);
    return r.f;
}
__device__ __forceinline__ int readlane_i32(int x, int sl) {
    return __builtin_amdgcn_readlane(x, __builtin_amdgcn_readfirstlane(sl));
}
// uniform-index select from a 16-entry register array
__device__ __forceinline__ int sel16(const int* p, int s) {
    int v = p[0];
    #pragma unroll
    for (int k = 1; k < K16; ++k) v = (s == k) ? p[k] : v;
    return v;
}

// Fused: 256-thread cost build (rows<32 -> LDS; rows>=32 -> same-XCD ctg),
// then SINGLE-WAVE Jonker-Volgenant.
// Fast path while v==0 everywhere (true until the first multi-step Dijkstra):
// r = ((0+(f64)c)-0)-0 = (f64)c, and f32->f64 is monotone+injective, so the
// argmin/ties computed in PURE F32 are bit-exact; minv = (double)gv32.
// After the first slow path (v becomes nonzero) a sticky flag switches to the
// full f64 fast path. Slow path = exact reference Dijkstra (unchanged).
template<bool HASWS>
__global__ __launch_bounds__(256) void matcher_fused(
    const float* __restrict__ obj, const float* __restrict__ cd,
    const float* __restrict__ gi, const int* __restrict__ ngt,
    float* __restrict__ ctg, float* __restrict__ out_ind,
    float* __restrict__ out_mask)
{
    __shared__ float ldsct[LROWS * 1025];            // 2-way bank alias: free
    __shared__ int   row4col_[Q_];                   // hops + final output
    __shared__ __align__(16) char scratch_[LROWS * 65 * 4]; // tile (build) / sh dump

    float (*tile)[65] = (float (*)[65])scratch_;
    double* sh_lds    = (double*)scratch_;

    const int b = blockIdx.x;
    const int t = threadIdx.x;
    const int l = t & 63;
    const int w = t >> 6;
    const int g = ngt[b];

    const float* objb = obj + (b << 10);
    const float* cdb  = cd + ((size_t)b << 16);
    const float* gib  = gi + ((size_t)b << 16);
    float* ctgb = HASWS ? (ctg + ((size_t)b << 15)) : (float*)nullptr;

    for (int j = t; j < Q_; j += T_) row4col_[j] = -1;

    // ---- build: all 256 threads; rows<32 direct to LDS, rows>=32 via tile ----
    if (g > 0) {
        const float4* cd4 = (const float4*)cdb;
        const float4* gi4 = (const float4*)gib;
        for (int jb = 0; jb < Q_; jb += 64) {
            #pragma unroll
            for (int p = 0; p < 4; ++p) {
                const int f  = t + (p << 8);
                const int jj = f >> 4;          // 0..63
                const int q  = f & 15;          // i-quad
                const int i0 = q << 2;          // 0,4,..,60
                const int j  = jb + jj;
                const float om = __fmul_rn(5.0f, -objb[j]);
                const float4 c4 = cd4[(j << 4) + q];
                const float4 q4 = gi4[(j << 4) + q];
                const float r0 = __fadd_rn(__fadd_rn(om, __fmul_rn(10.0f, c4.x)), __fmul_rn(2.0f, -q4.x));
                const float r1 = __fadd_rn(__fadd_rn(om, __fmul_rn(10.0f, c4.y)), __fmul_rn(2.0f, -q4.y));
                const float r2 = __fadd_rn(__fadd_rn(om, __fmul_rn(10.0f, c4.z)), __fmul_rn(2.0f, -q4.z));
                const float r3 = __fadd_rn(__fadd_rn(om, __fmul_rn(10.0f, c4.w)), __fmul_rn(2.0f, -q4.w));
                if (i0 < LROWS) {
                    ldsct[(i0 + 0) * 1025 + j] = r0;
                    ldsct[(i0 + 1) * 1025 + j] = r1;
                    ldsct[(i0 + 2) * 1025 + j] = r2;
                    ldsct[(i0 + 3) * 1025 + j] = r3;
                } else if (HASWS) {
                    tile[i0 - LROWS + 0][jj] = r0;
                    tile[i0 - LROWS + 1][jj] = r1;
                    tile[i0 - LROWS + 2][jj] = r2;
                    tile[i0 - LROWS + 3][jj] = r3;
                }
            }
            __syncthreads();
            if (HASWS) {
                #pragma unroll
                for (int r = 0; r < 8; ++r) {   // 32 rows x 64 cols / 256 thr
                    const int idx = (r << 8) + t;
                    const int i2 = idx >> 6, j2 = idx & 63;
                    if (LROWS + i2 < g)
                        ctgb[(i2 << 10) + jb + j2] = tile[i2][j2];   // coalesced
                }
            }
            __syncthreads();
        }
    }

    // ---- matcher: wave 0 only, zero barriers in the hot loop ----
    if (w == 0 && g > 0) {
        float objm[K16];
        if (!HASWS) {
            #pragma unroll
            for (int k = 0; k < K16; ++k) objm[k] = __fmul_rn(5.0f, -objb[l + (k << 6)]);
        }
        auto load_row = [&](int i, float* c) {
            if (i < LROWS) {
                #pragma unroll
                for (int k = 0; k < K16; ++k) c[k] = ldsct[i * 1025 + l + (k << 6)];
            } else if (HASWS) {
                #pragma unroll
                for (int k = 0; k < K16; ++k) c[k] = ctgb[((i - LROWS) << 10) + l + (k << 6)];
            } else {
                #pragma unroll
                for (int k = 0; k < K16; ++k) {
                    const int j = l + (k << 6);
                    const int idx = (j << 6) + i;
                    c[k] = __fadd_rn(__fadd_rn(objm[k], __fmul_rn(10.0f, cdb[idx])),
                                     __fmul_rn(2.0f, -gib[idx]));
                }
            }
        };
        // f64 argmin over cand[16] x 64 lanes (ties -> smallest j).
        auto lexmin64 = [&](const double* cand, double& gv_o, int& jm_o) {
            double t8[8];
            #pragma unroll
            for (int m = 0; m < 8; ++m) t8[m] = fmin(cand[2 * m], cand[2 * m + 1]);
            const double a4 = fmin(fmin(t8[0], t8[1]), fmin(t8[2], t8[3]));
            const double b4 = fmin(fmin(t8[4], t8[5]), fmin(t8[6], t8[7]));
            double bv = fmin(a4, b4);
            bv = fmin(bv, dpp_f64<ROR1>(bv));
            bv = fmin(bv, dpp_f64<ROR2>(bv));
            bv = fmin(bv, dpp_f64<ROR4>(bv));
            bv = fmin(bv, dpp_f64<ROR8>(bv));
            bv = fmin(bv, dpp_f64<BC15>(bv));
            bv = fmin(bv, dpp_f64<BC31>(bv));
            const double gv = readlane_f64(bv, 63);
            unsigned long long mk[K16];
            #pragma unroll
            for (int k = 0; k < K16; ++k) mk[k] = __ballot(cand[k] == gv);
            int jm = 0;
            #pragma unroll
            for (int k = K16 - 1; k >= 0; --k)
                if (mk[k]) jm = (k << 6) | (int)__builtin_ctzll(mk[k]);
            gv_o = gv; jm_o = jm;
        };

        const double INF = __builtin_inf();
        double u_rep   = 0.0;     // u[l]
        int    c4r_rep = -1;      // col4row[l]
        unsigned asg   = 0u;      // bit k: column l+64k assigned
        bool allv0     = true;    // wave-uniform: no v element nonzero yet
        double v_r[K16], sh_r[K16];
        int    path_r[K16];
        float  c_row[K16], c_next[K16];
        #pragma unroll
        for (int k = 0; k < K16; ++k) { v_r[k] = 0.0; path_r[k] = 0; }

        load_row(0, c_next);

        for (int cur = 0; cur < g; ++cur) {
            #pragma unroll
            for (int k = 0; k < K16; ++k) c_row[k] = c_next[k];
            if (cur + 1 < g) load_row(cur + 1, c_next);   // hides behind the row

            double minv; int jm;
            if (allv0) {
                // ---- pure-f32 argmin (bit-exact while v == 0) ----
                float t8[8];
                #pragma unroll
                for (int m = 0; m < 8; ++m) t8[m] = fminf(c_row[2 * m], c_row[2 * m + 1]);
                const float a4 = fminf(fminf(t8[0], t8[1]), fminf(t8[2], t8[3]));
                const float b4 = fminf(fminf(t8[4], t8[5]), fminf(t8[6], t8[7]));
                float bv = fminf(a4, b4);
                bv = fminf(bv, dpp_f32<ROR1>(bv));
                bv = fminf(bv, dpp_f32<ROR2>(bv));
                bv = fminf(bv, dpp_f32<ROR4>(bv));
                bv = fminf(bv, dpp_f32<ROR8>(bv));
                bv = fminf(bv, dpp_f32<BC15>(bv));
                bv = fminf(bv, dpp_f32<BC31>(bv));
                const float gv32 = readlane_f32(bv, 63);
                unsigned long long mk[K16];
                #pragma unroll
                for (int k = 0; k < K16; ++k) mk[k] = __ballot(c_row[k] == gv32);
                int j0 = 0;
                #pragma unroll
                for (int k = K16 - 1; k >= 0; --k)
                    if (mk[k]) j0 = (k << 6) | (int)__builtin_ctzll(mk[k]);
                jm = j0;
                minv = (double)gv32;       // exact: r = (double)c, conversion exact
            } else {
                double r[K16];
                #pragma unroll
                for (int k = 0; k < K16; ++k) r[k] = (double)c_row[k] - v_r[k];
                lexmin64(r, minv, jm);
            }

            const int owner0 = jm & 63, slot0 = jm >> 6;
            const unsigned oa0 = (unsigned)readlane_i32((int)asg, owner0);

            if (!((oa0 >> slot0) & 1u)) {
                // ---- 1-step row: O(1) state update (v provably unchanged) ----
                u_rep   = (l == cur)    ? u_rep + minv : u_rep;
                c4r_rep = (l == cur)    ? jm           : c4r_rep;
                asg     = (l == owner0) ? (asg | (1u << slot0)) : asg;
                if (l == 0) row4col_[jm] = cur;
            } else {
                // ---- slow path: materialize step-1 state, standard Dijkstra ----
                unsigned sc = 0u;
                if (allv0) {
                    #pragma unroll
                    for (int k = 0; k < K16; ++k) sh_r[k] = (double)c_row[k]; // v==0
                } else {
                    #pragma unroll
                    for (int k = 0; k < K16; ++k) sh_r[k] = (double)c_row[k] - v_r[k];
                }
                #pragma unroll
                for (int k = 0; k < K16; ++k) path_r[k] = cur;
                if (l == owner0) sc |= 1u << slot0;
                int i = row4col_[jm];
                bool inSR = (l == cur) || (l == i);
                double ui = readlane_f64(u_rep, i);
                load_row(i, c_row);
                int sink = -1;

                while (sink < 0) {
                    double cand[K16];
                    #pragma unroll
                    for (int k = 0; k < K16; ++k) {
                        const double rr = ((minv + (double)c_row[k]) - ui) - v_r[k];
                        const bool notSC = !((sc >> k) & 1u);
                        const bool upd = notSC && (rr < sh_r[k]);   // strict <
                        sh_r[k]   = upd ? rr : sh_r[k];
                        path_r[k] = upd ? i : path_r[k];
                        cand[k] = notSC ? sh_r[k] : INF;
                    }
                    lexmin64(cand, minv, jm);
                    if (l == (jm & 63)) sc |= 1u << (jm >> 6);
                    const unsigned oa = (unsigned)readlane_i32((int)asg, jm & 63);
                    if (!((oa >> (jm >> 6)) & 1u)) {
                        sink = jm;
                    } else {
                        i = row4col_[jm];
                        if (l == i) inSR = true;
                        ui = readlane_f64(u_rep, i);
                        load_row(i, c_row);
                    }
                }

                // dual updates (reference order: u, then v, then augment)
                if (l == cur) u_rep += minv;
                #pragma unroll
                for (int k = 0; k < K16; ++k) sh_lds[l + (k << 6)] = sh_r[k];
                __builtin_amdgcn_wave_barrier();
                if (inSR && l != cur) u_rep += minv - sh_lds[c4r_rep];
                __builtin_amdgcn_wave_barrier();
                #pragma unroll
                for (int k = 0; k < K16; ++k) {
                    const double nv = v_r[k] - (minv - sh_r[k]);
                    v_r[k] = ((sc >> k) & 1u) ? nv : v_r[k];
                }
                allv0 = false;   // v now (possibly) nonzero: use exact f64 path

                // augment along alternating path
                int j = sink;
                while (true) {
                    const int so = j & 63, ss = j >> 6;
                    const int ii = readlane_i32(sel16(path_r, ss), so);
                    const int nj = readlane_i32(c4r_rep, ii);   // old col4row[ii]
                    if (l == 0) row4col_[j] = ii;
                    if (l == so) asg |= 1u << ss;
                    if (l == ii) c4r_rep = j;
                    j = nj;
                    if (ii == cur) break;
                }
                __builtin_amdgcn_wave_barrier();
                // c_row clobbered by hop loads; c_next still holds row cur+1
            }
        }
    }

    __syncthreads();   // waves 1-3 park here; wave 0 arrives after matching
    for (int j = t; j < Q_; j += T_) {
        const int rc = row4col_[j];
        out_ind [(b << 10) + j] = (rc >= 0) ? (float)rc : 0.0f;
        out_mask[(b << 10) + j] = (rc >= 0) ? 1.0f : 0.0f;
    }
}

extern "C" void kernel_launch(void* const* d_in, const int* in_sizes, int n_in,
                              void* d_out, int out_size, void* d_ws, size_t ws_size,
                              hipStream_t stream)
{
    const float* obj = (const float*)d_in[1];
    const float* cd  = (const float*)d_in[2];
    const float* gi  = (const float*)d_in[3];
    const int*   ngt = (const int*)d_in[4];
    float* out0 = (float*)d_out;
    float* out1 = out0 + B_ * Q_;

    const size_t need = (size_t)B_ * (G_ - LROWS) * Q_ * sizeof(float);  // 4 MB
    if (ws_size >= need) {
        matcher_fused<true><<<B_, T_, 0, stream>>>(obj, cd, gi, ngt,
                                                   (float*)d_ws, out0, out1);
    } else {
        matcher_fused<false><<<B_, T_, 0, stream>>>(obj, cd, gi, ngt,
                                                    nullptr, out0, out1);
    }
}

// Round 13
// 167.443 us; speedup vs baseline: 1.2383x; 1.2383x over previous
//
#include <hip/hip_runtime.h>
#include <math.h>

#define B_ 32
#define Q_ 1024
#define G_ 64
#define K16 16   // columns per lane in matcher (Q_ / 64)

// ---- cross-lane helpers -------------------------------------------------
template<int CTRL>
__device__ __forceinline__ double dpp_f64(double x) {
    union { double d; int i[2]; } a; a.d = x;
    union { int i[2]; double d; } r;
    r.i[0] = __builtin_amdgcn_update_dpp(a.i[0], a.i[0], CTRL, 0xF, 0xF, false);
    r.i[1] = __builtin_amdgcn_update_dpp(a.i[1], a.i[1], CTRL, 0xF, 0xF, false);
    return r.d;
}
template<int CTRL>
__device__ __forceinline__ float dpp_f32(float x) {
    union { float f; int i; } a; a.f = x;
    union { int i; float f; } r;
    r.i = __builtin_amdgcn_update_dpp(a.i, a.i, CTRL, 0xF, 0xF, false);
    return r.f;
}
#define ROR1 0x121
#define ROR2 0x122
#define ROR4 0x124
#define ROR8 0x128
#define BC15 0x142
#define BC31 0x143

__device__ __forceinline__ double readlane_f64(double x, int sl) {
    const int s = __builtin_amdgcn_readfirstlane(sl);
    union { double d; int i2[2]; } a; a.d = x;
    union { int i2[2]; double d; } r;
    r.i2[0] = __builtin_amdgcn_readlane(a.i2[0], s);
    r.i2[1] = __builtin_amdgcn_readlane(a.i2[1], s);
    return r.d;
}
__device__ __forceinline__ float readlane_f32u(float x, int sl) {
    union { float f; int i; } a; a.f = x;
    union { int i; float f; } r;
    r.i = __builtin_amdgcn_readlane(a.i, __builtin_amdgcn_readfirstlane(sl));
    return r.f;
}
__device__ __forceinline__ float readlane_f32c(float x, int sl) {  // const lane
    union { float f; int i; } a; a.f = x;
    union { int i; float f; } r;
    r.i = __builtin_amdgcn_readlane(a.i, sl);
    return r.f;
}
__device__ __forceinline__ int readlane_i32(int x, int sl) {
    return __builtin_amdgcn_readlane(x, __builtin_amdgcn_readfirstlane(sl));
}
__device__ __forceinline__ int sel16(const int* p, int s) {
    int v = p[0];
    #pragma unroll
    for (int k = 1; k < K16; ++k) v = (s == k) ? p[k] : v;
    return v;
}

// K1: 512 blocks (16 jb-chunks x 32 batches). Builds transposed ct[b][i][j]
// (exact reference f32 arithmetic) AND per-row partial argmin over its 64-col
// chunk (strict <, ascending scan => first occurrence).
__global__ __launch_bounds__(256) void build_kernel(
    const float* __restrict__ obj, const float* __restrict__ cd,
    const float* __restrict__ gi, float* __restrict__ ct,
    float* __restrict__ pv, int* __restrict__ pj)
{
    __shared__ float tile[64][65];
    const int b  = blockIdx.y;
    const int jb = blockIdx.x << 6;
    const int t  = threadIdx.x;
    const float* objb = obj + (b << 10);
    const float4* cd4 = (const float4*)(cd + ((size_t)b << 16));
    const float4* gi4 = (const float4*)(gi + ((size_t)b << 16));

    #pragma unroll
    for (int p = 0; p < 4; ++p) {
        const int f  = t + (p << 8);
        const int jj = f >> 4;          // 0..63
        const int q  = f & 15;
        const int i0 = q << 2;          // 0,4,..,60
        const int j  = jb + jj;
        const float om = __fmul_rn(5.0f, -objb[j]);
        const float4 c4 = cd4[(j << 4) + q];
        const float4 q4 = gi4[(j << 4) + q];
        tile[i0 + 0][jj] = __fadd_rn(__fadd_rn(om, __fmul_rn(10.0f, c4.x)), __fmul_rn(2.0f, -q4.x));
        tile[i0 + 1][jj] = __fadd_rn(__fadd_rn(om, __fmul_rn(10.0f, c4.y)), __fmul_rn(2.0f, -q4.y));
        tile[i0 + 2][jj] = __fadd_rn(__fadd_rn(om, __fmul_rn(10.0f, c4.z)), __fmul_rn(2.0f, -q4.z));
        tile[i0 + 3][jj] = __fadd_rn(__fadd_rn(om, __fmul_rn(10.0f, c4.w)), __fmul_rn(2.0f, -q4.w));
    }
    __syncthreads();
    #pragma unroll
    for (int r = 0; r < 16; ++r) {      // coalesced ct write
        const int idx = (r << 8) + t;
        const int i = idx >> 6, j2 = idx & 63;
        ct[(((size_t)(b << 6) + i) << 10) + jb + j2] = tile[i][j2];
    }
    if (t < 64) {                        // partial argmin for row t
        float bv = tile[t][0]; int bc = 0;
        #pragma unroll 8
        for (int c = 1; c < 64; ++c) {
            const float v = tile[t][c];
            if (v < bv) { bv = v; bc = c; }   // strict <: first occurrence
        }
        const int o = (((b << 6) + t) << 4) + blockIdx.x;
        pv[o] = bv;
        pj[o] = jb + bc;
    }
}

// K2: 32 blocks x 1 wave. Per-row precomputed argmin + dirty-column tracking:
// a row's precomputed argmin stays bit-exact while v[pre_jm] is unchanged
// (v only decreases => r only increases on changed columns; first-occurrence
// minimum at an unchanged column is stable). Slow paths (collision or dirty
// argmin) run the exact f64 reference Dijkstra on ct rows.
template<bool HASWS>
__global__ __launch_bounds__(64) void matcher_k(
    const float* __restrict__ obj, const float* __restrict__ cd,
    const float* __restrict__ gi, const int* __restrict__ ngt,
    const float* __restrict__ ct, const float* __restrict__ pv,
    const int* __restrict__ pj, float* __restrict__ out_ind,
    float* __restrict__ out_mask)
{
    __shared__ int    row4col_[Q_];
    __shared__ double sh_lds[Q_];

    const int b = blockIdx.x;
    const int l = threadIdx.x;
    const int g = ngt[b];

    for (int j = l; j < Q_; j += 64) row4col_[j] = -1;
    __builtin_amdgcn_wave_barrier();

    const float* objb = obj + (b << 10);
    const float* cdb  = cd + ((size_t)b << 16);
    const float* gib  = gi + ((size_t)b << 16);
    const float* ctb  = HASWS ? (ct + ((size_t)(b << 6) << 10)) : (const float*)nullptr;

    float objm[K16];
    if (!HASWS) {
        #pragma unroll
        for (int k = 0; k < K16; ++k) objm[k] = __fmul_rn(5.0f, -objb[l + (k << 6)]);
    }
    auto load_row = [&](int i, float* c) {
        if (HASWS) {
            #pragma unroll
            for (int k = 0; k < K16; ++k) c[k] = ctb[((size_t)i << 10) + l + (k << 6)];
        } else {
            #pragma unroll
            for (int k = 0; k < K16; ++k) {
                const int j = l + (k << 6);
                const int idx = (j << 6) + i;
                c[k] = __fadd_rn(__fadd_rn(objm[k], __fmul_rn(10.0f, cdb[idx])),
                                 __fmul_rn(2.0f, -gib[idx]));
            }
        }
    };

    // ---- per-row precomputed argmin -> lane l holds row l's (val, j) ----
    float pre_v = 0.0f; int pre_j = 0;
    if (HASWS) {
        const float* pvb = pv + (((b << 6) + l) << 4);
        const int*   pjb = pj + (((b << 6) + l) << 4);
        float bv = pvb[0]; int bj = pjb[0];
        #pragma unroll
        for (int q = 1; q < 16; ++q) {
            const float v = pvb[q];
            const int  j = pjb[q];
            if (v < bv) { bv = v; bj = j; }   // ascending chunks: first occurrence
        }
        pre_v = bv; pre_j = bj;
    } else if (g > 0) {
        for (int i = 0; i < g; ++i) {         // fallback: cooperative per-row argmin
            float c[K16];
            load_row(i, c);
            float t8[8];
            #pragma unroll
            for (int m = 0; m < 8; ++m) t8[m] = fminf(c[2 * m], c[2 * m + 1]);
            float bv = fminf(fminf(fminf(t8[0], t8[1]), fminf(t8[2], t8[3])),
                             fminf(fminf(t8[4], t8[5]), fminf(t8[6], t8[7])));
            bv = fminf(bv, dpp_f32<ROR1>(bv));
            bv = fminf(bv, dpp_f32<ROR2>(bv));
            bv = fminf(bv, dpp_f32<ROR4>(bv));
            bv = fminf(bv, dpp_f32<ROR8>(bv));
            bv = fminf(bv, dpp_f32<BC15>(bv));
            bv = fminf(bv, dpp_f32<BC31>(bv));
            const float gv = readlane_f32c(bv, 63);
            unsigned long long mk[K16];
            #pragma unroll
            for (int k = 0; k < K16; ++k) mk[k] = __ballot(c[k] == gv);
            int j0 = 0;
            #pragma unroll
            for (int k = K16 - 1; k >= 0; --k)
                if (mk[k]) j0 = (k << 6) | (int)__builtin_ctzll(mk[k]);
            pre_v = (l == i) ? gv : pre_v;
            pre_j = (l == i) ? j0 : pre_j;
        }
    }

    // f64 argmin over cand[16] x 64 lanes (ties -> smallest j).
    auto lexmin64 = [&](const double* cand, double& gv_o, int& jm_o) {
        double t8[8];
        #pragma unroll
        for (int m = 0; m < 8; ++m) t8[m] = fmin(cand[2 * m], cand[2 * m + 1]);
        const double a4 = fmin(fmin(t8[0], t8[1]), fmin(t8[2], t8[3]));
        const double b4 = fmin(fmin(t8[4], t8[5]), fmin(t8[6], t8[7]));
        double bv = fmin(a4, b4);
        bv = fmin(bv, dpp_f64<ROR1>(bv));
        bv = fmin(bv, dpp_f64<ROR2>(bv));
        bv = fmin(bv, dpp_f64<ROR4>(bv));
        bv = fmin(bv, dpp_f64<ROR8>(bv));
        bv = fmin(bv, dpp_f64<BC15>(bv));
        bv = fmin(bv, dpp_f64<BC31>(bv));
        const double gv = readlane_f64(bv, 63);
        unsigned long long mk[K16];
        #pragma unroll
        for (int k = 0; k < K16; ++k) mk[k] = __ballot(cand[k] == gv);
        int jm = 0;
        #pragma unroll
        for (int k = K16 - 1; k >= 0; --k)
            if (mk[k]) jm = (k << 6) | (int)__builtin_ctzll(mk[k]);
        gv_o = gv; jm_o = jm;
    };

    const double INF = __builtin_inf();
    double u_rep   = 0.0;     // u[l]
    int    c4r_rep = -1;      // col4row[l]
    unsigned asg   = 0u;      // bit k: column l+64k assigned
    unsigned dirty = 0u;      // bit k: v of column l+64k has been modified
    double v_r[K16], sh_r[K16];
    int    path_r[K16];
    float  c_row[K16];
    #pragma unroll
    for (int k = 0; k < K16; ++k) { v_r[k] = 0.0; path_r[k] = 0; }

    for (int cur = 0; cur < g; ++cur) {
        // ---- precomputed step-1 argmin (valid unless its column is dirty) ----
        double minv = (double)readlane_f32u(pre_v, cur);
        int jm = readlane_i32(pre_j, cur);
        const unsigned dw = (unsigned)readlane_i32((int)dirty, jm & 63);
        if ((dw >> (jm >> 6)) & 1u) {
            // dirty argmin column: recompute exact f64 step-1 argmin
            load_row(cur, c_row);
            double r[K16];
            #pragma unroll
            for (int k = 0; k < K16; ++k) r[k] = (double)c_row[k] - v_r[k];
            lexmin64(r, minv, jm);
        }
        const int owner0 = jm & 63, slot0 = jm >> 6;
        const unsigned oa0 = (unsigned)readlane_i32((int)asg, owner0);

        if (!((oa0 >> slot0) & 1u)) {
            // ---- fast row: O(1) bookkeeping (u,v of others unchanged) ----
            u_rep   = (l == cur)    ? u_rep + minv : u_rep;
            c4r_rep = (l == cur)    ? jm           : c4r_rep;
            asg     = (l == owner0) ? (asg | (1u << slot0)) : asg;
            if (l == 0) row4col_[jm] = cur;
            __builtin_amdgcn_wave_barrier();
        } else {
            // ---- slow path: exact reference Dijkstra from step-1 state ----
            load_row(cur, c_row);
            unsigned sc = 0u;
            #pragma unroll
            for (int k = 0; k < K16; ++k) {
                sh_r[k] = (double)c_row[k] - v_r[k];
                path_r[k] = cur;
            }
            if (l == owner0) sc |= 1u << slot0;
            int i = row4col_[jm];
            bool inSR = (l == cur) || (l == i);
            double ui = readlane_f64(u_rep, i);
            load_row(i, c_row);
            int sink = -1;

            while (sink < 0) {
                double cand[K16];
                #pragma unroll
                for (int k = 0; k < K16; ++k) {
                    const double rr = ((minv + (double)c_row[k]) - ui) - v_r[k];
                    const bool notSC = !((sc >> k) & 1u);
                    const bool upd = notSC && (rr < sh_r[k]);   // strict <
                    sh_r[k]   = upd ? rr : sh_r[k];
                    path_r[k] = upd ? i : path_r[k];
                    cand[k] = notSC ? sh_r[k] : INF;
                }
                lexmin64(cand, minv, jm);
                if (l == (jm & 63)) sc |= 1u << (jm >> 6);
                const unsigned oa = (unsigned)readlane_i32((int)asg, jm & 63);
                if (!((oa >> (jm >> 6)) & 1u)) {
                    sink = jm;
                } else {
                    i = row4col_[jm];
                    if (l == i) inSR = true;
                    ui = readlane_f64(u_rep, i);
                    load_row(i, c_row);
                }
            }

            // dual updates (reference order: u, then v, then augment)
            if (l == cur) u_rep += minv;
            #pragma unroll
            for (int k = 0; k < K16; ++k) sh_lds[l + (k << 6)] = sh_r[k];
            __builtin_amdgcn_wave_barrier();
            if (inSR && l != cur) u_rep += minv - sh_lds[c4r_rep];
            __builtin_amdgcn_wave_barrier();
            #pragma unroll
            for (int k = 0; k < K16; ++k) {
                const double nv = v_r[k] - (minv - sh_r[k]);
                v_r[k] = ((sc >> k) & 1u) ? nv : v_r[k];
            }
            dirty |= sc;   // conservative: all SC columns considered modified

            // augment along alternating path
            int j = sink;
            while (true) {
                const int so = j & 63, ss = j >> 6;
                const int ii = readlane_i32(sel16(path_r, ss), so);
                const int nj = readlane_i32(c4r_rep, ii);   // old col4row[ii]
                if (l == 0) row4col_[j] = ii;
                if (l == so) asg |= 1u << ss;
                if (l == ii) c4r_rep = j;
                j = nj;
                if (ii == cur) break;
            }
            __builtin_amdgcn_wave_barrier();
        }
    }

    __builtin_amdgcn_wave_barrier();
    for (int j = l; j < Q_; j += 64) {
        const int rc = row4col_[j];
        out_ind [(b << 10) + j] = (rc >= 0) ? (float)rc : 0.0f;
        out_mask[(b << 10) + j] = (rc >= 0) ? 1.0f : 0.0f;
    }
}

extern "C" void kernel_launch(void* const* d_in, const int* in_sizes, int n_in,
                              void* d_out, int out_size, void* d_ws, size_t ws_size,
                              hipStream_t stream)
{
    const float* obj = (const float*)d_in[1];
    const float* cd  = (const float*)d_in[2];
    const float* gi  = (const float*)d_in[3];
    const int*   ngt = (const int*)d_in[4];
    float* out0 = (float*)d_out;
    float* out1 = out0 + B_ * Q_;

    const size_t ct_b = (size_t)B_ * G_ * Q_ * sizeof(float);       // 8 MB
    const size_t pv_b = (size_t)B_ * G_ * 16 * sizeof(float);       // 128 KB
    if (ws_size >= ct_b + 2 * pv_b) {
        float* ct = (float*)d_ws;
        float* pv = (float*)((char*)d_ws + ct_b);
        int*   pj = (int*)((char*)d_ws + ct_b + pv_b);
        build_kernel<<<dim3(16, B_), 256, 0, stream>>>(obj, cd, gi, ct, pv, pj);
        matcher_k<true><<<B_, 64, 0, stream>>>(obj, cd, gi, ngt, ct, pv, pj, out0, out1);
    } else {
        matcher_k<false><<<B_, 64, 0, stream>>>(obj, cd, gi, ngt,
                                                nullptr, nullptr, nullptr, out0, out1);
    }
}